// Round 25
// baseline (6249.454 us; speedup 1.0000x reference)
//
#include <hip/hip_runtime.h>

#define NB 32
#define NPTS 131072
#define KSAMP 2048
#define NPART 8
#define TPB 512
#define NPT 32                    // points per thread
#define PART_PTS (NPTS / NPART)   // 16384
#define BATCH_F (NPTS * 3)
#define NWAVE 64                  // publishing waves per batch (8 parts x 8)

// R25 = R22/R24 with the block-level aggregation stage deleted.
// Every wave publishes its DPP wave-max key DIRECTLY to a 64-slot global
// row (gid = part*8 + wave); only each block's wave0 polls the row (8
// pollers/batch -- R21/R23's 64-poller explosion avoided; other waves wait
// on R24's proven LDS mailbox). Removes barrier1 + wred + wave0's 8-key
// pre-reduce from the serial path: the slowest wave's key reaches L2 right
// after its scan instead of after {barrier, reduce, re-store}.
//
// WAR inductions (same shape as R10/R24 proofs):
//  row: wave w rewrites row[k&1] at k+2 only after exiting mailbox-spin
//   (k+1) <= its wave0 completed row-spin(k+1) <= all 64 waves published
//   k+1 <= every block's wave0 already exited row-spin(k) (program order).
//  mailbox: wave0 rewrites mbox[k&1] at k+2 only after row-spin(k+2) <=
//   all waves published k+2 <= all waves exited mailbox-spin(k+1) >= (k).
// Tags 1..2047 (bits 17..31) disambiguate 0xAA poison (tag 0x5555) and
// stale replay data (deterministic replays are bitwise-identical anyway).
//
// DPP fast-path argmax (R22-validated, bit-exact): v_max_f32 DPP chain
// (sd>=0 so bound_ctrl:0 zero-injection is max-identity) -> readlane(63)
// -> ballot -> unique (tie density ~1e-5): winner via readlane/shfl ==
// u64-tree winner; tied: PROVEN u64 tree fallback (exact first-index).
// Row reduce compares tagged keys; tags equal across slots -> exact.
//
// Numerics (bit-exact validated R4/R10):
//   d2  = fma(dz,dz, fma(dx,dx, dy*dy))   (LLVM-canonical contraction)
//   md2 = fminf(md2, d2); ONE CR sqrt per thread -> ref sd domain
//   key = (sd_bits<<32)|(131071-n): u64-max == jnp.argmax value+first-index

#define RPT32(X) X(0)X(1)X(2)X(3)X(4)X(5)X(6)X(7)X(8)X(9)X(10)X(11)X(12) \
  X(13)X(14)X(15)X(16)X(17)X(18)X(19)X(20)X(21)X(22)X(23)X(24)X(25)X(26) \
  X(27)X(28)X(29)X(30)X(31)

// Wave-wide f32 max (all 64 lanes active, x >= 0). Returns uniform max.
__device__ __forceinline__ float wave_max_f32(float x) {
  float v = x;
  asm volatile(
      "s_nop 1\n\t"
      "v_max_f32 %0, %0, %0 row_shr:1 bound_ctrl:0\n\t"
      "s_nop 1\n\t"
      "v_max_f32 %0, %0, %0 row_shr:2 bound_ctrl:0\n\t"
      "s_nop 1\n\t"
      "v_max_f32 %0, %0, %0 row_shr:4 bound_ctrl:0\n\t"
      "s_nop 1\n\t"
      "v_max_f32 %0, %0, %0 row_shr:8 bound_ctrl:0\n\t"
      "s_nop 1\n\t"
      "v_max_f32 %0, %0, %0 row_bcast:15 row_mask:0xa bound_ctrl:0\n\t"
      "s_nop 1\n\t"
      "v_max_f32 %0, %0, %0 row_bcast:31 row_mask:0xc bound_ctrl:0\n\t"
      "s_nop 1"
      : "+v"(v));
  return __uint_as_float(
      (unsigned)__builtin_amdgcn_readlane(__float_as_uint(v), 63));
}

__global__ __launch_bounds__(TPB)
__attribute__((amdgpu_waves_per_eu(2, 2)))
void fps_kernel(
    const float* __restrict__ x, const int* __restrict__ start,
    int* __restrict__ out, unsigned long long* __restrict__ slot)
{
  #pragma clang fp contract(off)
  const int blk  = blockIdx.x;
  // XCD-clustered: all 8 parts of a batch share blk&7 (same XCD under
  // round-robin dispatch) -> sync row + x slice get L2 locality.
  const int xcd  = blk & 7;
  const int j    = blk >> 3;          // 0..31
  const int b    = xcd * 4 + (j & 3); // 0..31
  const int part = j >> 2;            // 0..7
  const int tid  = threadIdx.x;
  const int lane = tid & 63;
  const int wave = tid >> 6;
  const int gid  = part * 8 + wave;   // 0..63: this wave's publish slot

  const float* xb = x + (size_t)b * BATCH_F;

  // start_idx dtype hedge: int64 (LE, <2^31) => zeros at odd int32 slots.
  bool is64 = true;
  #pragma unroll 1
  for (int i = 1; i < 32; i += 2) {
    if (start[i] != 0) { is64 = false; break; }
  }
  int cur = is64 ? start[2 * b] : start[b];

  const int base = part * PART_PTS + tid;

  #define DECLP(J) float px##J, py##J, pz##J, md2##J;
  RPT32(DECLP)
  #define INITP(J) { const int n = base + (J) * TPB;          \
      px##J = xb[3*n]; py##J = xb[3*n+1]; pz##J = xb[3*n+2];  \
      md2##J = __builtin_inff(); }
  RPT32(INITP)

  __shared__ float bcx[2], bcy[2], bcz[2];
  __shared__ unsigned bct[2];          // mailbox tag word: (tag<<17)|nidx

  if (tid == 0) { bct[0] = 0; bct[1] = 0; }

  if (part == 0 && tid == 0) out[b * KSAMP] = cur;  // scan emits idx BEFORE update

  float cx = xb[3 * (size_t)cur + 0];
  float cy = xb[3 * (size_t)cur + 1];
  float cz = xb[3 * (size_t)cur + 2];

  // slot layout: [b][2][64] u64 (32 KB total)
  unsigned long long* const srow0 = slot + (size_t)b * 2 * NWAVE;

  __syncthreads();   // mailbox init visible

  for (int k = 0; k < KSAMP - 1; ++k) {
    float bestv = -1.0f;   // d^2 domain
    int   bestn = 0;
    #define SCANP(J) {                                              \
      const float dx = px##J - cx;                                  \
      const float dy = py##J - cy;                                  \
      const float dz = pz##J - cz;                                  \
      const float d2 = fmaf(dz, dz, fmaf(dx, dx, dy * dy));         \
      const float m  = fminf(md2##J, d2);                           \
      md2##J = m;                                                   \
      if (m > bestv) { bestv = m; bestn = base + (J) * TPB; }       \
    }
    RPT32(SCANP)

    const float sdw = sqrtf(bestv);   // ONE CR sqrt -> ref sd domain

    // ---- wave argmax: DPP fast path, exact u64-tree fallback on ties ----
    const float vmax = wave_max_f32(sdw);
    const unsigned long long tie = __ballot(sdw == vmax);
    unsigned long long key;
    if (__popcll(tie) == 1) {
      const int wl = __ffsll((long long)tie) - 1;
      const unsigned bn = (unsigned)__builtin_amdgcn_readlane(bestn, wl);
      key = ((unsigned long long)__float_as_uint(vmax) << 32) |
            (unsigned)(NPTS - 1 - (int)bn);
    } else {
      key = ((unsigned long long)__float_as_uint(sdw) << 32) |
            (unsigned)(NPTS - 1 - bestn);
      #pragma unroll
      for (int off = 32; off >= 1; off >>= 1) {
        const unsigned long long o = __shfl_xor(key, off, 64);
        if (o > key) key = o;
      }
    }

    const unsigned tag = (unsigned)(k + 1);       // 1..2047, never 0x5555
    const int kb = k & 1;
    unsigned long long* const row = srow0 + (unsigned)kb * NWAVE;

    // Direct per-wave publish: no barrier, no block-level pre-reduce.
    if (lane == 0)
      __hip_atomic_store(&row[gid], key | ((unsigned long long)tag << 17),
                         __ATOMIC_RELAXED, __HIP_MEMORY_SCOPE_AGENT);

    if (wave == 0) {
      // wave0-only poll of all 64 slots (one coalesced 512B load/iter).
      unsigned long long g;
      do {
        g = __hip_atomic_load(&row[lane], __ATOMIC_RELAXED,
                              __HIP_MEMORY_SCOPE_AGENT);
      } while (__ballot(((unsigned)(g >> 17) & 0x7FFFu) == tag) != ~0ull);

      // ---- argmax over 64 tagged keys: DPP fast path, tree fallback ----
      const float sg = __uint_as_float((unsigned)(g >> 32));
      const float mg = wave_max_f32(sg);
      const unsigned long long tg = __ballot(sg == mg);
      unsigned long long win;
      if (__popcll(tg) == 1) {
        win = __shfl(g, __ffsll((long long)tg) - 1, 64);
      } else {
        win = g;   // tags equal across slots -> raw u64 compare exact
        #pragma unroll
        for (int off = 32; off >= 1; off >>= 1) {
          const unsigned long long o = __shfl_xor(win, off, 64);
          if (o > win) win = o;
        }
      }
      const int nidx = NPTS - 1 - (int)(win & 0x1FFFFu);
      if (part == 0 && lane == 0) out[b * KSAMP + k + 1] = nidx;

      // uniform L2 fetch (one line, broadcast across wave0's lanes)
      const float ncx = xb[3 * (size_t)nidx + 0];
      const float ncy = xb[3 * (size_t)nidx + 1];
      const float ncz = xb[3 * (size_t)nidx + 2];
      if (lane == 0) {
        bcx[kb] = ncx; bcy[kb] = ncy; bcz[kb] = ncz;
        __hip_atomic_store(&bct[kb], (tag << 17) | (unsigned)nidx,
                           __ATOMIC_RELEASE, __HIP_MEMORY_SCOPE_WORKGROUP);
      }
      cx = ncx; cy = ncy; cz = ncz;
    } else {
      // LDS mailbox spin: local, zero L2 traffic, ~30cy pickup (R24-proven).
      unsigned t;
      do {
        t = __hip_atomic_load(&bct[kb], __ATOMIC_ACQUIRE,
                              __HIP_MEMORY_SCOPE_WORKGROUP);
      } while ((t >> 17) != tag);
      cx = bcx[kb]; cy = bcy[kb]; cz = bcz[kb];
    }
  }
}

extern "C" void kernel_launch(void* const* d_in, const int* in_sizes, int n_in,
                              void* d_out, int out_size, void* d_ws, size_t ws_size,
                              hipStream_t stream) {
  const float* x     = (const float*)d_in[0];
  const int*   start = (const int*)d_in[1];
  int*         out   = (int*)d_out;
  unsigned long long* slot = (unsigned long long*)d_ws;  // [32][2][64] u64 = 32KB

  // No memset needed: step tags (1..2047 in bits 17..31) disambiguate the
  // 0xAA poison (tag 0x5555) and stale values from prior replays (which are
  // bitwise-identical across deterministic replays anyway).
  void* args[] = {(void*)&x, (void*)&start, (void*)&out, (void*)&slot};
  hipLaunchCooperativeKernel((void*)fps_kernel, dim3(NB * NPART), dim3(TPB),
                             args, 0, stream);
}

// Round 26
// 4343.453 us; speedup vs baseline: 1.4388x; 1.4388x over previous
//
#include <hip/hip_runtime.h>

#define NB 32
#define NPTS 131072
#define KSAMP 2048
#define NPART 8
#define TPB 512
#define NPT 32                    // points per thread
#define PART_PTS (NPTS / NPART)   // 16384
#define BATCH_F (NPTS * 3)

// R26 = R22 verbatim (champion, 4341us, bit-exact). Final form after the
// protocol search concluded:
//  - R21/R23/R25 (flatten a hierarchy stage) all regressed: block-level
//    pre-reduction compresses the publish-arrival tail; wave0-only global
//    polling minimizes L2 poll traffic; barrier fanout beats alternatives.
//  - R14 (NPART=16, 2 blocks/CU), R16-R18 (SoA/LDS data paths), R19/R20
//    (exact pruning): all flat or worse. Step floor = register scan
//    (~0.65us, issue-bound) + one agent-scope rendezvous across 8 CUs
//    (~1.45us) -- a latency floor, not a BW/compute roofline.
//
// Structure: 8 blocks x 512 threads per batch (256-block cooperative grid,
// 1 block/CU). Per step: register scan -> DPP wave argmax -> LDS -> wave0
// cross-wave argmax -> tagged publish (agent relaxed store) -> wave0 spins
// on the 64B row until all 8 tags match -> row argmax -> snext broadcast ->
// barrier -> uniform L2 centroid fetch.
//
// DPP fast-path argmax (bit-exact): v_max_f32 DPP chain (sd>=0 so
// bound_ctrl:0 zero-injection is max-identity) -> readlane(63) -> ballot
// -> unique (tie density ~1e-5): winner via readlane == u64-tree winner;
// tied: PROVEN u64 tree fallback (exact first-index).
//
// Numerics (bit-exact vs XLA reference, validated R4/R10/R22):
//   d2  = fma(dz,dz, fma(dx,dx, dy*dy))   (LLVM-canonical contraction)
//   md2 = fminf(md2, d2); ONE CR sqrt per thread -> ref sd domain
//   key = (sd_bits<<32)|(131071-n): u64-max == jnp.argmax value+first-index
//
// Tags 1..2047 (bits 17..31) disambiguate 0xAA poison (tag 0x5555) and
// stale replay data; double-buffered rows kill WAR (row k&1 rewritten only
// at k+2, after all parts exited spin k). No workspace memset needed.

#define RPT32(X) X(0)X(1)X(2)X(3)X(4)X(5)X(6)X(7)X(8)X(9)X(10)X(11)X(12) \
  X(13)X(14)X(15)X(16)X(17)X(18)X(19)X(20)X(21)X(22)X(23)X(24)X(25)X(26) \
  X(27)X(28)X(29)X(30)X(31)

// Wave-wide f32 max (all 64 lanes active, x >= 0). Returns uniform max.
__device__ __forceinline__ float wave_max_f32(float x) {
  float v = x;
  asm volatile(
      "s_nop 1\n\t"
      "v_max_f32 %0, %0, %0 row_shr:1 bound_ctrl:0\n\t"
      "s_nop 1\n\t"
      "v_max_f32 %0, %0, %0 row_shr:2 bound_ctrl:0\n\t"
      "s_nop 1\n\t"
      "v_max_f32 %0, %0, %0 row_shr:4 bound_ctrl:0\n\t"
      "s_nop 1\n\t"
      "v_max_f32 %0, %0, %0 row_shr:8 bound_ctrl:0\n\t"
      "s_nop 1\n\t"
      "v_max_f32 %0, %0, %0 row_bcast:15 row_mask:0xa bound_ctrl:0\n\t"
      "s_nop 1\n\t"
      "v_max_f32 %0, %0, %0 row_bcast:31 row_mask:0xc bound_ctrl:0\n\t"
      "s_nop 1"
      : "+v"(v));
  return __uint_as_float(
      (unsigned)__builtin_amdgcn_readlane(__float_as_uint(v), 63));
}

__global__ __launch_bounds__(TPB)
__attribute__((amdgpu_waves_per_eu(2, 2)))
void fps_kernel(
    const float* __restrict__ x, const int* __restrict__ start,
    int* __restrict__ out, unsigned long long* __restrict__ slot)
{
  #pragma clang fp contract(off)
  const int blk  = blockIdx.x;
  // XCD-clustered: all 8 parts of a batch share blk&7 (same XCD under
  // round-robin dispatch) -> sync row + x slice get L2 locality.
  const int xcd  = blk & 7;
  const int j    = blk >> 3;          // 0..31
  const int b    = xcd * 4 + (j & 3); // 0..31
  const int part = j >> 2;            // 0..7
  const int tid  = threadIdx.x;
  const int lane = tid & 63;
  const int wave = tid >> 6;

  const float* xb = x + (size_t)b * BATCH_F;

  // start_idx dtype hedge: int64 (LE, <2^31) => zeros at odd int32 slots.
  bool is64 = true;
  #pragma unroll 1
  for (int i = 1; i < 32; i += 2) {
    if (start[i] != 0) { is64 = false; break; }
  }
  int cur = is64 ? start[2 * b] : start[b];

  const int base = part * PART_PTS + tid;

  #define DECLP(J) float px##J, py##J, pz##J, md2##J;
  RPT32(DECLP)
  #define INITP(J) { const int n = base + (J) * TPB;          \
      px##J = xb[3*n]; py##J = xb[3*n+1]; pz##J = xb[3*n+2];  \
      md2##J = __builtin_inff(); }
  RPT32(INITP)

  __shared__ unsigned long long wred[TPB / 64];
  __shared__ int snext;

  if (part == 0 && tid == 0) out[b * KSAMP] = cur;  // scan emits idx BEFORE update

  float cx = xb[3 * (size_t)cur + 0];
  float cy = xb[3 * (size_t)cur + 1];
  float cz = xb[3 * (size_t)cur + 2];

  unsigned long long* const srow0 = slot + (size_t)b * 2 * NPART;  // [b][2][8]

  for (int k = 0; k < KSAMP - 1; ++k) {
    float bestv = -1.0f;   // d^2 domain
    int   bestn = 0;
    #define SCANP(J) {                                              \
      const float dx = px##J - cx;                                  \
      const float dy = py##J - cy;                                  \
      const float dz = pz##J - cz;                                  \
      const float d2 = fmaf(dz, dz, fmaf(dx, dx, dy * dy));         \
      const float m  = fminf(md2##J, d2);                           \
      md2##J = m;                                                   \
      if (m > bestv) { bestv = m; bestn = base + (J) * TPB; }       \
    }
    RPT32(SCANP)

    const float sdw = sqrtf(bestv);   // ONE CR sqrt -> ref sd domain

    // ---- wave argmax: DPP fast path, exact u64-tree fallback on ties ----
    const float vmax = wave_max_f32(sdw);
    const unsigned long long tie = __ballot(sdw == vmax);
    unsigned long long key;
    if (__popcll(tie) == 1) {
      const int wl = __ffsll((long long)tie) - 1;
      const unsigned bn = (unsigned)__builtin_amdgcn_readlane(bestn, wl);
      key = ((unsigned long long)__float_as_uint(vmax) << 32) |
            (unsigned)(NPTS - 1 - (int)bn);
    } else {
      key = ((unsigned long long)__float_as_uint(sdw) << 32) |
            (unsigned)(NPTS - 1 - bestn);
      #pragma unroll
      for (int off = 32; off >= 1; off >>= 1) {
        const unsigned long long o = __shfl_xor(key, off, 64);
        if (o > key) key = o;
      }
    }
    if (lane == 0) wred[wave] = key;
    __syncthreads();

    if (wave == 0) {
      // ---- cross-wave argmax over 8 keys (lanes hold wred[lane&7]) ----
      unsigned long long v = wred[lane & 7];
      const float sv = __uint_as_float((unsigned)(v >> 32));
      const float mv = wave_max_f32(sv);
      const unsigned long long t8 = __ballot(sv == mv) & 0xFFull;
      unsigned long long bk;
      if (__popcll(t8) == 1) {
        bk = __shfl(v, __ffsll((long long)t8) - 1, 64);
      } else {
        bk = v;
        #pragma unroll
        for (int off = 4; off >= 1; off >>= 1) {
          const unsigned long long o = __shfl_xor(bk, off, 64);
          if (o > bk) bk = o;
        }
      }

      const unsigned tag = (unsigned)(k + 1);     // 1..2047, never 0x5555
      unsigned long long* const row = srow0 + (unsigned)(k & 1) * NPART;
      if (lane == 0)
        __hip_atomic_store(&row[part], bk | ((unsigned long long)tag << 17),
                           __ATOMIC_RELAXED, __HIP_MEMORY_SCOPE_AGENT);

      // parallel spin on the 64B row until all 8 tags match this step.
      unsigned long long g;
      do {
        g = __hip_atomic_load(&row[lane & (NPART - 1)], __ATOMIC_RELAXED,
                              __HIP_MEMORY_SCOPE_AGENT);
      } while (__ballot(((unsigned)(g >> 17) & 0x7FFFu) == tag) != ~0ull);

      // ---- argmax over 8 slots: DPP fast path, tree fallback ----
      const float sg = __uint_as_float((unsigned)(g >> 32));
      const float mg = wave_max_f32(sg);
      const unsigned long long t8b = __ballot(sg == mg) & 0xFFull;
      unsigned long long win;
      if (__popcll(t8b) == 1) {
        win = __shfl(g, __ffsll((long long)t8b) - 1, 64);
      } else {
        win = g;   // tags equal across slots -> raw u64 compare exact
        #pragma unroll
        for (int off = 4; off >= 1; off >>= 1) {
          const unsigned long long o = __shfl_xor(win, off, 64);
          if (o > win) win = o;
        }
      }
      const int nidx = NPTS - 1 - (int)(win & 0x1FFFFu);
      if (lane == 0) {
        snext = nidx;
        if (part == 0) out[b * KSAMP + k + 1] = nidx;
      }
    }
    __syncthreads();

    const int nidx = snext;
    cx = xb[3 * (size_t)nidx + 0];
    cy = xb[3 * (size_t)nidx + 1];
    cz = xb[3 * (size_t)nidx + 2];
  }
}

extern "C" void kernel_launch(void* const* d_in, const int* in_sizes, int n_in,
                              void* d_out, int out_size, void* d_ws, size_t ws_size,
                              hipStream_t stream) {
  const float* x     = (const float*)d_in[0];
  const int*   start = (const int*)d_in[1];
  int*         out   = (int*)d_out;
  unsigned long long* slot = (unsigned long long*)d_ws;  // [32][2][8] u64 = 4KB

  // No memset needed: step tags (1..2047 in bits 17..31) disambiguate the
  // 0xAA poison (tag 0x5555) and stale values from prior replays (which are
  // bitwise-identical across deterministic replays anyway).
  void* args[] = {(void*)&x, (void*)&start, (void*)&out, (void*)&slot};
  hipLaunchCooperativeKernel((void*)fps_kernel, dim3(NB * NPART), dim3(TPB),
                             args, 0, stream);
}